// Round 5
// baseline (205.913 us; speedup 1.0000x reference)
//
#include <hip/hip_runtime.h>
#include <hip/hip_bf16.h>

#define B_ 2
#define T_ 2048
#define C_ 1024
#define H_ 16
#define DV_ 64
#define KW_ 31

typedef __attribute__((ext_vector_type(8))) short bf16x8;
typedef __attribute__((ext_vector_type(4))) float f32x4;

__device__ inline short f2bf(float f) {
    __hip_bfloat16 h = __float2bfloat16(f);
    return *reinterpret_cast<short*>(&h);
}

__device__ inline void async16(const void* g, void* l) {
    __builtin_amdgcn_global_load_lds(
        (const __attribute__((address_space(1))) unsigned int*)g,
        (__attribute__((address_space(3))) unsigned int*)l, 16, 0, 0);
}

// ---------------------------------------------------------------- conv (register sliding window)
#define TCV 32
__global__ __launch_bounds__(256) void conv_kernel(
        const float* __restrict__ x, const float* __restrict__ w,
        const float* __restrict__ bias, float* __restrict__ out) {
    int b = blockIdx.y >> 2;
    int c0 = (blockIdx.y & 3) * 256;
    int t0 = blockIdx.x * TCV;
    int tid = threadIdx.x;
    __shared__ float wl[256 * KW_];
    for (int i = tid; i < 256 * KW_; i += 256) wl[i] = w[c0 * KW_ + i];
    __syncthreads();
    float wr[KW_];
#pragma unroll
    for (int k = 0; k < KW_; k++) wr[k] = wl[tid * KW_ + k];
    int c = c0 + tid;
    float bi = bias[c];
    float acc[TCV];
#pragma unroll
    for (int t = 0; t < TCV; t++) acc[t] = bi;
    const float* xp = x + (size_t)b * T_ * C_ + c;
#pragma unroll
    for (int i = 0; i < TCV + KW_ - 1; i++) {
        int tt = t0 + i - 15;
        float xv = (tt >= 0 && tt < T_) ? xp[(size_t)tt * C_] : 0.f;
        int lo = (i - (KW_ - 1) > 0) ? i - (KW_ - 1) : 0;
        int hi = (i < TCV - 1) ? i : TCV - 1;
#pragma unroll
        for (int t = lo; t <= hi; t++)
            acc[t] = fmaf(xv, wr[i - t], acc[t]);
    }
    float* op = out + ((size_t)b * T_ + t0) * C_ + c;
#pragma unroll
    for (int t = 0; t < TCV; t++) op[(size_t)t * C_] = acc[t];
}

// ---------------------------------------------------------------- f32 -> bf16
__global__ __launch_bounds__(256) void cvt_kernel(
        const float* __restrict__ in, short* __restrict__ out) {
    int i = blockIdx.x * 256 + threadIdx.x;
    float4 v0 = ((const float4*)in)[i * 2];
    float4 v1 = ((const float4*)in)[i * 2 + 1];
    bf16x8 o;
    o[0] = f2bf(v0.x); o[1] = f2bf(v0.y); o[2] = f2bf(v0.z); o[3] = f2bf(v0.w);
    o[4] = f2bf(v1.x); o[5] = f2bf(v1.y); o[6] = f2bf(v1.z); o[7] = f2bf(v1.w);
    ((bf16x8*)out)[i] = o;
}

// ---------------------------------------------------------------- pack q_w||kv_w -> bf16 (64,1024)
__global__ __launch_bounds__(256) void qkcvt_kernel(
        const float* __restrict__ qw, const float* __restrict__ kw,
        short* __restrict__ qkw) {
    int i = blockIdx.x * 256 + threadIdx.x;
    int n = i >> 7;
    int k8 = (i & 127) * 8;
    const float* src = (n < 32 ? qw + (size_t)n * C_ : kw + (size_t)(n - 32) * C_) + k8;
    float4 v0 = *(const float4*)src;
    float4 v1 = *(const float4*)(src + 4);
    bf16x8 o;
    o[0] = f2bf(v0.x); o[1] = f2bf(v0.y); o[2] = f2bf(v0.z); o[3] = f2bf(v0.w);
    o[4] = f2bf(v1.x); o[5] = f2bf(v1.y); o[6] = f2bf(v1.z); o[7] = f2bf(v1.w);
    ((bf16x8*)qkw)[i] = o;
}

// ---------------------------------------------------------------- q/k proj via MFMA
// q -> qo row-major (B*T,32); k -> kbT [(b*16+h)*2+d][T] (transposed for attn)
__global__ __launch_bounds__(256) void qkproj_kernel(
        const short* __restrict__ A, const short* __restrict__ Wq,
        const float* __restrict__ qbias, const float* __restrict__ kbias,
        float* __restrict__ qo, float* __restrict__ kbT) {
    __shared__ short At[128 * 32];
    __shared__ short Wt[64 * 32];
    int tid = threadIdx.x;
    int w = tid >> 6, l = tid & 63;
    int i0 = blockIdx.x * 128;
    int R0 = w * 32;
    const int xorb = (((l >> 4) ^ (l & 3)) << 4);
    int srow = l >> 2, schunk = l & 3;

    f32x4 acc[2][4];
#pragma unroll
    for (int m = 0; m < 2; m++)
#pragma unroll
        for (int n = 0; n < 4; n++) acc[m][n] = (f32x4){0.f, 0.f, 0.f, 0.f};

    for (int k0 = 0; k0 < C_; k0 += 32) {
#pragma unroll
        for (int half = 0; half < 2; half++) {
            int rr = half * 64 + w * 16 + srow;
            int gch = schunk ^ (rr & 3);
            async16((const char*)(A + (size_t)(i0 + rr) * C_ + k0) + gch * 16,
                    (char*)At + half * 4096 + w * 1024);
        }
        {
            int rr = w * 16 + srow;
            int gch = schunk ^ (rr & 3);
            async16((const char*)(Wq + (size_t)rr * C_ + k0) + gch * 16,
                    (char*)Wt + w * 1024);
        }
        __syncthreads();
        bf16x8 afr[2], bfr[4];
#pragma unroll
        for (int m = 0; m < 2; m++)
            afr[m] = *(const bf16x8*)((char*)At + (R0 + m * 16 + (l & 15)) * 64 + xorb);
#pragma unroll
        for (int n = 0; n < 4; n++)
            bfr[n] = *(const bf16x8*)((char*)Wt + (n * 16 + (l & 15)) * 64 + xorb);
#pragma unroll
        for (int m = 0; m < 2; m++)
#pragma unroll
            for (int n = 0; n < 4; n++)
                acc[m][n] = __builtin_amdgcn_mfma_f32_16x16x32_bf16(afr[m], bfr[n], acc[m][n], 0, 0, 0);
        __syncthreads();
    }
#pragma unroll
    for (int n = 0; n < 4; n++) {
        int col = n * 16 + (l & 15);
        float bj = (col < 32) ? qbias[col] : kbias[col - 32];
#pragma unroll
        for (int m = 0; m < 2; m++) {
            int rbase = i0 + R0 + m * 16 + ((l >> 4) << 2);
#pragma unroll
            for (int g = 0; g < 4; g++) {
                float z = acc[m][n][g] + bj;
                int row = rbase + g;
                if (col < 32) {
                    qo[(size_t)row * 32 + col] = z;
                } else {
                    int cc = col - 32, hh = cc >> 1, dd = cc & 1;
                    int bb_ = row >> 11, tt = row & (T_ - 1);
                    kbT[(((size_t)bb_ * 16 + hh) * 2 + dd) * T_ + tt] = z;
                }
            }
        }
    }
}

// ---------------------------------------------------------------- V transpose: x (B,T,C) -> xvt (B*H, 64, T) bf16
__global__ __launch_bounds__(256) void vtrans_kernel(
        const float* __restrict__ x, short* __restrict__ xvt) {
    int bh = blockIdx.y;
    int b = bh >> 4, h = bh & 15;
    int t0 = blockIdx.x * 64;
    __shared__ float ldsT[64][65];
    int tid = threadIdx.x;
    int tl = tid >> 2;
    int d0 = (tid & 3) * 16;
    const float* xp = x + ((size_t)(b * T_ + t0 + tl)) * C_ + h * 64 + d0;
#pragma unroll
    for (int q = 0; q < 4; q++) {
        float4 v = *(const float4*)(xp + q * 4);
        ldsT[d0 + q * 4 + 0][tl] = v.x;
        ldsT[d0 + q * 4 + 1][tl] = v.y;
        ldsT[d0 + q * 4 + 2][tl] = v.z;
        ldsT[d0 + q * 4 + 3][tl] = v.w;
    }
    __syncthreads();
    int d = tid >> 2;
    int ts = (tid & 3) * 16;
    short* op = xvt + ((size_t)bh * 64 + d) * T_ + t0 + ts;
    bf16x8 o0, o1;
#pragma unroll
    for (int q = 0; q < 8; q++) {
        o0[q] = f2bf(ldsT[d][ts + q]);
        o1[q] = f2bf(ldsT[d][ts + 8 + q]);
    }
    *(bf16x8*)op = o0;
    *(bf16x8*)(op + 8) = o1;
}

// ---------------------------------------------------------------- attention
// QBLK=128 rows/block, 4 waves x 32 rows, KV tile 64. P lives in registers:
// lane l computes scores for rows {R0+m*16+(l&15)} at kv {ks*32+(l>>4)*8..+7}
// == exactly the MFMA A-fragment layout. K read from global (L1-hot kbT).
__global__ __launch_bounds__(256) void attn_kernel(
        const float* __restrict__ qbuf, const float* __restrict__ kbT,
        const short* __restrict__ xvt, float* __restrict__ xatt) {
    int bh = blockIdx.y;
    int b = bh >> 4, h = bh & 15;
    int t0 = ((int)gridDim.x - 1 - (int)blockIdx.x) * 128;
    int tid = threadIdx.x;
    int w = tid >> 6, l = tid & 63;
    int l15 = l & 15, l4 = l >> 4;

    __shared__ short V_lds[2 * 64 * 64];    // [buf][dv][kv], rows 128B, slot^=(dv&7)
    __shared__ float red_lds[128];
    char* Vb = (char*)V_lds;

    const float scale = 0.02209708691f * 1.44269504089f;  // 1/sqrt(T) * log2e
    int R0 = w * 32;
    float qx[2], qy[2];
#pragma unroll
    for (int m = 0; m < 2; m++) {
        float2 q2 = *(const float2*)(qbuf + ((size_t)(b * T_ + t0 + R0 + m * 16 + l15)) * 32 + h * 2);
        qx[m] = q2.x * scale;
        qy[m] = q2.y * scale;
    }
    const float* k0p = kbT + ((size_t)bh * 2) * T_;
    const float* k1p = k0p + T_;

    f32x4 acc[2][4];
#pragma unroll
    for (int m = 0; m < 2; m++)
#pragma unroll
        for (int n = 0; n < 4; n++) acc[m][n] = (f32x4){0.f, 0.f, 0.f, 0.f};
    float lrun[2] = {0.f, 0.f};

    // V staging: wave w covers dv rows w*16..+15 via 2 asyncs (8 rows each)
    const char* vs0 = (const char*)xvt
        + ((((size_t)bh * 64 + w * 16 + (l >> 3)) * T_) + (size_t)(((l & 7) ^ (l >> 3)) * 8)) * 2;
    const char* vs1 = vs0 + (size_t)8 * T_ * 2;

    int nt = t0 / 64 + 2;

    // prologue: stage tile 0 -> buf 0
    async16(vs0, Vb + w * 2048);
    async16(vs1, Vb + w * 2048 + 1024);
    __syncthreads();

    for (int t = 0; t < nt; t++) {
        int buf = t & 1;
        int s0 = t * 64;
        if (t + 1 < nt) {
            size_t go = (size_t)(s0 + 64) * 2;
            async16(vs0 + go, Vb + (buf ^ 1) * 8192 + w * 2048);
            async16(vs1 + go, Vb + (buf ^ 1) * 8192 + w * 2048 + 1024);
        }
        // ---- scores -> P (registers, A-fragment layout)
        float kx[2][8], ky[2][8];
#pragma unroll
        for (int ks = 0; ks < 2; ks++) {
            int base = s0 + ks * 32 + l4 * 8;
            *(float4*)&kx[ks][0] = *(const float4*)(k0p + base);
            *(float4*)&kx[ks][4] = *(const float4*)(k0p + base + 4);
            *(float4*)&ky[ks][0] = *(const float4*)(k1p + base);
            *(float4*)&ky[ks][4] = *(const float4*)(k1p + base + 4);
        }
        bf16x8 afr[2][2];
        bool dom = (t >= nt - 2);
        int soff = s0 - t0;
#pragma unroll
        for (int m = 0; m < 2; m++) {
            int rloc = R0 + m * 16 + l15;
            float ls = 0.f;
#pragma unroll
            for (int ks = 0; ks < 2; ks++) {
                int kbase = soff + ks * 32 + l4 * 8;
#pragma unroll
                for (int i = 0; i < 8; i++) {
                    float sc = fmaf(qx[m], kx[ks][i], qy[m] * ky[ks][i]);
                    float p = exp2f(sc);
                    if (dom) p = (kbase + i <= rloc) ? p : 0.f;
                    ls += p;
                    afr[m][ks][i] = f2bf(p);
                }
            }
            lrun[m] += ls;
        }
        // ---- PV MFMA
#pragma unroll
        for (int n = 0; n < 4; n++) {
            int dv = n * 16 + l15;
            int sl0 = (l4) ^ (dv & 7);
            int sl1 = (4 + l4) ^ (dv & 7);
            bf16x8 b0 = *(const bf16x8*)(Vb + buf * 8192 + dv * 128 + sl0 * 16);
            bf16x8 b1 = *(const bf16x8*)(Vb + buf * 8192 + dv * 128 + sl1 * 16);
#pragma unroll
            for (int m = 0; m < 2; m++) {
                acc[m][n] = __builtin_amdgcn_mfma_f32_16x16x32_bf16(afr[m][0], b0, acc[m][n], 0, 0, 0);
                acc[m][n] = __builtin_amdgcn_mfma_f32_16x16x32_bf16(afr[m][1], b1, acc[m][n], 0, 0, 0);
            }
        }
        __syncthreads();
    }
    // epilogue: row sums -> normalize -> store
#pragma unroll
    for (int m = 0; m < 2; m++) {
        lrun[m] += __shfl_xor(lrun[m], 16);
        lrun[m] += __shfl_xor(lrun[m], 32);
        if (l4 == 0) red_lds[R0 + m * 16 + l15] = lrun[m];
    }
#pragma unroll
    for (int m = 0; m < 2; m++) {
#pragma unroll
        for (int g = 0; g < 4; g++) {
            int row = R0 + m * 16 + l4 * 4 + g;
            float inv = 1.f / red_lds[row];
            int trow = t0 + row;
#pragma unroll
            for (int n = 0; n < 4; n++) {
                int col = h * 64 + n * 16 + l15;
                xatt[((size_t)(b * T_ + trow)) * C_ + col] = acc[m][n][g] * inv;
            }
        }
    }
}

// ---------------------------------------------------------------- bf16 MFMA GEMM  out = A(M,K)*W(N,K)^T
// 128x128 tile, BK=32, 512 thr (8 waves 2Mx4N), double-buffered 2-phase.
template <int MODE>
__global__ __launch_bounds__(512) void mgemm_kernel(
        const short* __restrict__ A, const short* __restrict__ W,
        const float* __restrict__ bias, short* __restrict__ outb,
        float* __restrict__ out32,
        const float* __restrict__ e0, const float* __restrict__ e1,
        const float* __restrict__ e2, const float* __restrict__ e3) {
    __shared__ short At[2 * 128 * 32];      // 2 x 8KB, rows 64B, slot = chunk^(row&3)
    __shared__ short Wt[2 * 128 * 32];
    int tid = threadIdx.x;
    int w = tid >> 6, l = tid & 63;
    int wm = w >> 2, wn = w & 3;
    int l15 = l & 15, l4 = l >> 4;
    int i0 = blockIdx.y * 128, j0 = blockIdx.x * 128;
    const int xorb = ((l4 ^ (l15 & 3)) << 4);
    int srow = tid >> 2, sch = (tid & 3) ^ (srow & 3);
    const char* asrc = (const char*)(A + (size_t)(i0 + srow) * C_) + sch * 16;
    const char* wsrc = (const char*)(W + (size_t)(j0 + srow) * C_) + sch * 16;
    char* Ab = (char*)At;
    char* Wb = (char*)Wt;

    f32x4 acc[4][2];
#pragma unroll
    for (int m = 0; m < 4; m++)
#pragma unroll
        for (int n = 0; n < 2; n++) acc[m][n] = (f32x4){0.f, 0.f, 0.f, 0.f};

    // prologue
    async16(asrc, Ab + w * 1024);
    async16(wsrc, Wb + w * 1024);
    __syncthreads();

    for (int ks = 0; ks < 32; ks++) {
        int buf = ks & 1;
        if (ks + 1 < 32) {
            size_t go = (size_t)(ks + 1) * 64;     // 32 bf16 = 64 bytes
            async16(asrc + go, Ab + (buf ^ 1) * 8192 + w * 1024);
            async16(wsrc + go, Wb + (buf ^ 1) * 8192 + w * 1024);
        }
        bf16x8 a[4], bv[2];
#pragma unroll
        for (int m = 0; m < 4; m++)
            a[m] = *(const bf16x8*)(Ab + buf * 8192 + (wm * 64 + m * 16 + l15) * 64 + xorb);
#pragma unroll
        for (int n = 0; n < 2; n++)
            bv[n] = *(const bf16x8*)(Wb + buf * 8192 + (wn * 32 + n * 16 + l15) * 64 + xorb);
#pragma unroll
        for (int m = 0; m < 4; m++)
#pragma unroll
            for (int n = 0; n < 2; n++)
                acc[m][n] = __builtin_amdgcn_mfma_f32_16x16x32_bf16(a[m], bv[n], acc[m][n], 0, 0, 0);
        __syncthreads();
    }
    // epilogue
#pragma unroll
    for (int n = 0; n < 2; n++) {
        int col = j0 + wn * 32 + n * 16 + l15;
        float bj = bias[col];
        float tdv = (MODE == 1) ? e3[col] : 0.f;
#pragma unroll
        for (int m = 0; m < 4; m++) {
            int rbase = i0 + wm * 64 + m * 16 + l4 * 4;
#pragma unroll
            for (int g = 0; g < 4; g++) {
                size_t off = (size_t)(rbase + g) * C_ + col;
                float z = acc[m][n][g] + bj;
                if (MODE == 0) {
                    z = z / (1.f + __expf(-z));
                    outb[off] = f2bf(z);
                } else if (MODE == 1) {
                    float comb = e0[off] + 0.5f * e1[off] + 0.5f * z;
                    z = comb * tdv + e2[off] * (1.f - tdv);
                    outb[off] = f2bf(z);
                } else {
                    out32[off] = z;
                }
            }
        }
    }
}

// ---------------------------------------------------------------- layernorm + residual
__global__ __launch_bounds__(256) void ln_kernel(
        const float* __restrict__ proj, const float* __restrict__ x,
        const float* __restrict__ g, const float* __restrict__ bb,
        float* __restrict__ out) {
    int row = blockIdx.x;
    int tid = threadIdx.x;
    const float* pr = proj + (size_t)row * C_;
    float4 v = *(const float4*)(pr + tid * 4);
    float s = v.x + v.y + v.z + v.w;
    float s2 = v.x * v.x + v.y * v.y + v.z * v.z + v.w * v.w;
#pragma unroll
    for (int off = 32; off > 0; off >>= 1) {
        s += __shfl_down(s, off);
        s2 += __shfl_down(s2, off);
    }
    __shared__ float ws0[4], ws1[4];
    int wid = tid >> 6;
    if ((tid & 63) == 0) { ws0[wid] = s; ws1[wid] = s2; }
    __syncthreads();
    s = ws0[0] + ws0[1] + ws0[2] + ws0[3];
    s2 = ws1[0] + ws1[1] + ws1[2] + ws1[3];
    float mu = s * (1.f / C_);
    float var = s2 * (1.f / C_) - mu * mu;
    float rs = rsqrtf(var + 1e-5f);
    int c = tid * 4;
    float4 xr = *(const float4*)(x + (size_t)row * C_ + c);
    float4 gg = *(const float4*)(g + c);
    float4 bv = *(const float4*)(bb + c);
    float4 o;
    o.x = (v.x - mu) * rs * gg.x + bv.x + xr.x;
    o.y = (v.y - mu) * rs * gg.y + bv.y + xr.y;
    o.z = (v.z - mu) * rs * gg.z + bv.z + xr.z;
    o.w = (v.w - mu) * rs * gg.w + bv.w + xr.w;
    *(float4*)(out + (size_t)row * C_ + c) = o;
}

// ---------------------------------------------------------------- launch
extern "C" void kernel_launch(void* const* d_in, const int* in_sizes, int n_in,
                              void* d_out, int out_size, void* d_ws, size_t ws_size,
                              hipStream_t stream) {
    const float* x      = (const float*)d_in[0];
    const float* conv_w = (const float*)d_in[1];
    const float* conv_b = (const float*)d_in[2];
    const float* q_w    = (const float*)d_in[3];
    const float* q_b    = (const float*)d_in[4];
    const float* kv_w   = (const float*)d_in[5];
    const float* kv_b   = (const float*)d_in[6];
    const float* mem_w1 = (const float*)d_in[7];
    const float* mem_b1 = (const float*)d_in[8];
    const float* mem_w2 = (const float*)d_in[9];
    const float* mem_b2 = (const float*)d_in[10];
    const float* out_w  = (const float*)d_in[11];
    const float* out_b  = (const float*)d_in[12];
    const float* ln_g   = (const float*)d_in[13];
    const float* ln_b   = (const float*)d_in[14];
    const float* td     = (const float*)d_in[15];
    float* out = (float*)d_out;

    const size_t NTC = (size_t)B_ * T_ * C_;      // 4M
    char* p = (char*)d_ws;
    float* xconv = (float*)p;            p += NTC * 4;
    float* xatt  = (float*)p;            p += NTC * 4;
    float* proj  = (float*)p;            p += NTC * 4;
    float* qb_   = (float*)p;            p += (size_t)B_ * T_ * 32 * 4;
    float* kbT   = (float*)p;            p += (size_t)B_ * H_ * 2 * T_ * 4;
    short* xbf   = (short*)p;            p += NTC * 2;
    short* y1bf  = (short*)p;            p += NTC * 2;
    short* combbf= (short*)p;            p += NTC * 2;
    short* xvt   = (short*)p;            p += NTC * 2;
    short* wbf1  = (short*)p;            p += (size_t)C_ * C_ * 2;
    short* wbf2  = (short*)p;            p += (size_t)C_ * C_ * 2;
    short* wbf3  = (short*)p;            p += (size_t)C_ * C_ * 2;
    short* qkw   = (short*)p;            p += (size_t)64 * C_ * 2;

    const int WN8 = (C_ * C_) / 8 / 256;
    cvt_kernel<<<(int)(NTC / 8 / 256), 256, 0, stream>>>(x, xbf);
    cvt_kernel<<<WN8, 256, 0, stream>>>(mem_w1, wbf1);
    cvt_kernel<<<WN8, 256, 0, stream>>>(mem_w2, wbf2);
    cvt_kernel<<<WN8, 256, 0, stream>>>(out_w, wbf3);
    qkcvt_kernel<<<(64 * C_) / 8 / 256, 256, 0, stream>>>(q_w, kv_w, qkw);
    vtrans_kernel<<<dim3(T_ / 64, B_ * H_), 256, 0, stream>>>(x, xvt);
    conv_kernel<<<dim3(T_ / TCV, B_ * (C_ / 256)), 256, 0, stream>>>(x, conv_w, conv_b, xconv);
    qkproj_kernel<<<(B_ * T_) / 128, 256, 0, stream>>>(xbf, qkw, q_b, kv_b, qb_, kbT);
    attn_kernel<<<dim3(T_ / 128, B_ * H_), 256, 0, stream>>>(qb_, kbT, xvt, xatt);
    mgemm_kernel<0><<<dim3(C_ / 128, (B_ * T_) / 128), 512, 0, stream>>>(
        xbf, wbf1, mem_b1, y1bf, nullptr, nullptr, nullptr, nullptr, nullptr);
    mgemm_kernel<1><<<dim3(C_ / 128, (B_ * T_) / 128), 512, 0, stream>>>(
        y1bf, wbf2, mem_b2, combbf, nullptr, xconv, xatt, x, td);
    mgemm_kernel<2><<<dim3(C_ / 128, (B_ * T_) / 128), 512, 0, stream>>>(
        combbf, wbf3, out_b, nullptr, proj, nullptr, nullptr, nullptr, nullptr);
    ln_kernel<<<B_ * T_, 256, 0, stream>>>(proj, x, ln_g, ln_b, out);
}

// Round 6
// 182.187 us; speedup vs baseline: 1.1302x; 1.1302x over previous
//
#include <hip/hip_runtime.h>
#include <hip/hip_bf16.h>

#define B_ 2
#define T_ 2048
#define C_ 1024
#define H_ 16
#define DV_ 64
#define KW_ 31

typedef __attribute__((ext_vector_type(8))) short bf16x8;
typedef __attribute__((ext_vector_type(4))) float f32x4;

__device__ inline short f2bf(float f) {
    __hip_bfloat16 h = __float2bfloat16(f);
    return *reinterpret_cast<short*>(&h);
}

__device__ inline void async16(const void* g, void* l) {
    __builtin_amdgcn_global_load_lds(
        (const __attribute__((address_space(1))) unsigned int*)g,
        (__attribute__((address_space(3))) unsigned int*)l, 16, 0, 0);
}

// ---------------------------------------------------------------- conv (register sliding window)
#define TCV 32
__global__ __launch_bounds__(256) void conv_kernel(
        const float* __restrict__ x, const float* __restrict__ w,
        const float* __restrict__ bias, float* __restrict__ out) {
    int b = blockIdx.y >> 2;
    int c0 = (blockIdx.y & 3) * 256;
    int t0 = blockIdx.x * TCV;
    int tid = threadIdx.x;
    __shared__ float wl[256 * KW_];
    for (int i = tid; i < 256 * KW_; i += 256) wl[i] = w[c0 * KW_ + i];
    __syncthreads();
    float wr[KW_];
#pragma unroll
    for (int k = 0; k < KW_; k++) wr[k] = wl[tid * KW_ + k];
    int c = c0 + tid;
    float bi = bias[c];
    float acc[TCV];
#pragma unroll
    for (int t = 0; t < TCV; t++) acc[t] = bi;
    const float* xp = x + (size_t)b * T_ * C_ + c;
#pragma unroll
    for (int i = 0; i < TCV + KW_ - 1; i++) {
        int tt = t0 + i - 15;
        float xv = (tt >= 0 && tt < T_) ? xp[(size_t)tt * C_] : 0.f;
        int lo = (i - (KW_ - 1) > 0) ? i - (KW_ - 1) : 0;
        int hi = (i < TCV - 1) ? i : TCV - 1;
#pragma unroll
        for (int t = lo; t <= hi; t++)
            acc[t] = fmaf(xv, wr[i - t], acc[t]);
    }
    float* op = out + ((size_t)b * T_ + t0) * C_ + c;
#pragma unroll
    for (int t = 0; t < TCV; t++) op[(size_t)t * C_] = acc[t];
}

// ---------------------------------------------------------------- f32 -> bf16
__global__ __launch_bounds__(256) void cvt_kernel(
        const float* __restrict__ in, short* __restrict__ out) {
    int i = blockIdx.x * 256 + threadIdx.x;
    float4 v0 = ((const float4*)in)[i * 2];
    float4 v1 = ((const float4*)in)[i * 2 + 1];
    bf16x8 o;
    o[0] = f2bf(v0.x); o[1] = f2bf(v0.y); o[2] = f2bf(v0.z); o[3] = f2bf(v0.w);
    o[4] = f2bf(v1.x); o[5] = f2bf(v1.y); o[6] = f2bf(v1.z); o[7] = f2bf(v1.w);
    ((bf16x8*)out)[i] = o;
}

// ---------------------------------------------------------------- pack q_w||kv_w -> bf16 (64,1024)
__global__ __launch_bounds__(256) void qkcvt_kernel(
        const float* __restrict__ qw, const float* __restrict__ kw,
        short* __restrict__ qkw) {
    int i = blockIdx.x * 256 + threadIdx.x;
    int n = i >> 7;
    int k8 = (i & 127) * 8;
    const float* src = (n < 32 ? qw + (size_t)n * C_ : kw + (size_t)(n - 32) * C_) + k8;
    float4 v0 = *(const float4*)src;
    float4 v1 = *(const float4*)(src + 4);
    bf16x8 o;
    o[0] = f2bf(v0.x); o[1] = f2bf(v0.y); o[2] = f2bf(v0.z); o[3] = f2bf(v0.w);
    o[4] = f2bf(v1.x); o[5] = f2bf(v1.y); o[6] = f2bf(v1.z); o[7] = f2bf(v1.w);
    ((bf16x8*)qkw)[i] = o;
}

// ---------------------------------------------------------------- q/k proj via MFMA
// q -> qo row-major (B*T,32); k -> kbT [(b*16+h)*2+d][T]
__global__ __launch_bounds__(256) void qkproj_kernel(
        const short* __restrict__ A, const short* __restrict__ Wq,
        const float* __restrict__ qbias, const float* __restrict__ kbias,
        float* __restrict__ qo, float* __restrict__ kbT) {
    __shared__ short At[128 * 32];
    __shared__ short Wt[64 * 32];
    int tid = threadIdx.x;
    int w = tid >> 6, l = tid & 63;
    int i0 = blockIdx.x * 128;
    int R0 = w * 32;
    const int xorb = (((l >> 4) ^ (l & 3)) << 4);
    int srow = l >> 2, schunk = l & 3;

    f32x4 acc[2][4];
#pragma unroll
    for (int m = 0; m < 2; m++)
#pragma unroll
        for (int n = 0; n < 4; n++) acc[m][n] = (f32x4){0.f, 0.f, 0.f, 0.f};

    for (int k0 = 0; k0 < C_; k0 += 32) {
#pragma unroll
        for (int half = 0; half < 2; half++) {
            int rr = half * 64 + w * 16 + srow;
            int gch = schunk ^ (rr & 3);
            async16((const char*)(A + (size_t)(i0 + rr) * C_ + k0) + gch * 16,
                    (char*)At + half * 4096 + w * 1024);
        }
        {
            int rr = w * 16 + srow;
            int gch = schunk ^ (rr & 3);
            async16((const char*)(Wq + (size_t)rr * C_ + k0) + gch * 16,
                    (char*)Wt + w * 1024);
        }
        __syncthreads();
        bf16x8 afr[2], bfr[4];
#pragma unroll
        for (int m = 0; m < 2; m++)
            afr[m] = *(const bf16x8*)((char*)At + (R0 + m * 16 + (l & 15)) * 64 + xorb);
#pragma unroll
        for (int n = 0; n < 4; n++)
            bfr[n] = *(const bf16x8*)((char*)Wt + (n * 16 + (l & 15)) * 64 + xorb);
#pragma unroll
        for (int m = 0; m < 2; m++)
#pragma unroll
            for (int n = 0; n < 4; n++)
                acc[m][n] = __builtin_amdgcn_mfma_f32_16x16x32_bf16(afr[m], bfr[n], acc[m][n], 0, 0, 0);
        __syncthreads();
    }
#pragma unroll
    for (int n = 0; n < 4; n++) {
        int col = n * 16 + (l & 15);
        float bj = (col < 32) ? qbias[col] : kbias[col - 32];
#pragma unroll
        for (int m = 0; m < 2; m++) {
            int rbase = i0 + R0 + m * 16 + ((l >> 4) << 2);
#pragma unroll
            for (int g = 0; g < 4; g++) {
                float z = acc[m][n][g] + bj;
                int row = rbase + g;
                if (col < 32) {
                    qo[(size_t)row * 32 + col] = z;
                } else {
                    int cc = col - 32, hh = cc >> 1, dd = cc & 1;
                    int bb_ = row >> 11, tt = row & (T_ - 1);
                    kbT[(((size_t)bb_ * 16 + hh) * 2 + dd) * T_ + tt] = z;
                }
            }
        }
    }
}

// ---------------------------------------------------------------- V transpose: x (B,T,C) -> xvt (B*H, 64, T) bf16
__global__ __launch_bounds__(256) void vtrans_kernel(
        const float* __restrict__ x, short* __restrict__ xvt) {
    int bh = blockIdx.y;
    int b = bh >> 4, h = bh & 15;
    int t0 = blockIdx.x * 64;
    __shared__ float ldsT[64][65];
    int tid = threadIdx.x;
    int tl = tid >> 2;
    int d0 = (tid & 3) * 16;
    const float* xp = x + ((size_t)(b * T_ + t0 + tl)) * C_ + h * 64 + d0;
#pragma unroll
    for (int q = 0; q < 4; q++) {
        float4 v = *(const float4*)(xp + q * 4);
        ldsT[d0 + q * 4 + 0][tl] = v.x;
        ldsT[d0 + q * 4 + 1][tl] = v.y;
        ldsT[d0 + q * 4 + 2][tl] = v.z;
        ldsT[d0 + q * 4 + 3][tl] = v.w;
    }
    __syncthreads();
    int d = tid >> 2;
    int ts = (tid & 3) * 16;
    short* op = xvt + ((size_t)bh * 64 + d) * T_ + t0 + ts;
    bf16x8 o0, o1;
#pragma unroll
    for (int q = 0; q < 8; q++) {
        o0[q] = f2bf(ldsT[d][ts + q]);
        o1[q] = f2bf(ldsT[d][ts + 8 + q]);
    }
    *(bf16x8*)op = o0;
    *(bf16x8*)(op + 8) = o1;
}

// ---------------------------------------------------------------- attention (KV-split, no-max softmax)
// QBLK=64 rows, 4 waves x 16 rows. KV chunk = 512 (8 tiles of 64).
// blockIdx.x in [0,80) encodes (tb,ck); reversed so heavy blocks go first.
// Single-chunk tb (<8): write normalized xatt. Else: fp32 partial + l partial.
__global__ __launch_bounds__(256) void attn_kernel(
        const float* __restrict__ qbuf, const float* __restrict__ kbT,
        const short* __restrict__ xvt, float* __restrict__ xatt,
        float* __restrict__ part, float* __restrict__ lpart) {
    int bh = blockIdx.y;
    int b = bh >> 4, h = bh & 15;
    int idx = 79 - (int)blockIdx.x;
    int tb, ck;
    if (idx < 8)       { tb = idx;                ck = 0; }
    else if (idx < 24) { tb = 8 + ((idx - 8) >> 1);  ck = (idx - 8) & 1; }
    else if (idx < 48) { tb = 16 + (idx - 24) / 3;   ck = (idx - 24) % 3; }
    else               { tb = 24 + ((idx - 48) >> 2); ck = (idx - 48) & 3; }
    int t0 = tb * 64;
    int kvs = ck * 512;
    int kve = min(kvs + 512, t0 + 64);
    int ntiles = (kve - kvs) >> 6;
    bool dom = (kve == t0 + 64);
    bool single = (tb < 8);

    int tid = threadIdx.x;
    int w = tid >> 6, l = tid & 63;
    int l15 = l & 15, l4 = l >> 4;

    __shared__ short V_lds[2 * 64 * 64];    // [buf][dv][kv] rows 128B, slot^=(dv&7)
    __shared__ float red_lds[64];
    char* Vb = (char*)V_lds;

    const float scale = 0.02209708691f * 1.44269504089f;  // 1/sqrt(T) * log2e
    int rloc = w * 16 + l15;
    float2 q2 = *(const float2*)(qbuf + ((size_t)(b * T_ + t0 + rloc)) * 32 + h * 2);
    float qx = q2.x * scale, qy = q2.y * scale;
    const float* k0p = kbT + ((size_t)bh * 2) * T_;
    const float* k1p = k0p + T_;

    f32x4 acc[4];
#pragma unroll
    for (int n = 0; n < 4; n++) acc[n] = (f32x4){0.f, 0.f, 0.f, 0.f};
    float lrun = 0.f;

    // V staging: wave w covers dv rows w*16..+15 via 2 asyncs
    const char* vs0 = (const char*)xvt
        + ((((size_t)bh * 64 + w * 16 + (l >> 3)) * T_) + (size_t)(kvs + ((l & 7) ^ (l >> 3)) * 8)) * 2;
    const char* vs1 = vs0 + (size_t)8 * T_ * 2;

    async16(vs0, Vb + w * 2048);
    async16(vs1, Vb + w * 2048 + 1024);
    __syncthreads();

    for (int t = 0; t < ntiles; t++) {
        int buf = t & 1;
        if (t + 1 < ntiles) {
            size_t go = (size_t)((t + 1) * 64) * 2;
            async16(vs0 + go, Vb + (buf ^ 1) * 8192 + w * 2048);
            async16(vs1 + go, Vb + (buf ^ 1) * 8192 + w * 2048 + 1024);
        }
        // scores -> P registers (A-fragment layout)
        float kx[2][8], ky[2][8];
#pragma unroll
        for (int ks = 0; ks < 2; ks++) {
            int base = kvs + t * 64 + ks * 32 + l4 * 8;
            *(float4*)&kx[ks][0] = *(const float4*)(k0p + base);
            *(float4*)&kx[ks][4] = *(const float4*)(k0p + base + 4);
            *(float4*)&ky[ks][0] = *(const float4*)(k1p + base);
            *(float4*)&ky[ks][4] = *(const float4*)(k1p + base + 4);
        }
        bf16x8 afr[2];
        bool msk = dom && (t == ntiles - 1);
        int soff = kvs + t * 64 - t0;
        float ls = 0.f;
#pragma unroll
        for (int ks = 0; ks < 2; ks++) {
            int kbase = soff + ks * 32 + l4 * 8;
#pragma unroll
            for (int i = 0; i < 8; i++) {
                float sc = fmaf(qx, kx[ks][i], qy * ky[ks][i]);
                float p = exp2f(sc);
                if (msk) p = (kbase + i <= rloc) ? p : 0.f;
                ls += p;
                afr[ks][i] = f2bf(p);
            }
        }
        lrun += ls;
        // PV MFMA
#pragma unroll
        for (int n = 0; n < 4; n++) {
            int dv = n * 16 + l15;
            int sl0 = (l4) ^ (dv & 7);
            int sl1 = (4 + l4) ^ (dv & 7);
            bf16x8 b0 = *(const bf16x8*)(Vb + buf * 8192 + dv * 128 + sl0 * 16);
            bf16x8 b1 = *(const bf16x8*)(Vb + buf * 8192 + dv * 128 + sl1 * 16);
            acc[n] = __builtin_amdgcn_mfma_f32_16x16x32_bf16(afr[0], b0, acc[n], 0, 0, 0);
            acc[n] = __builtin_amdgcn_mfma_f32_16x16x32_bf16(afr[1], b1, acc[n], 0, 0, 0);
        }
        __syncthreads();
    }
    // row sums across l4 groups
    lrun += __shfl_xor(lrun, 16);
    lrun += __shfl_xor(lrun, 32);

    if (single) {
        if (l4 == 0) red_lds[rloc] = lrun;
        __syncthreads();
#pragma unroll
        for (int g = 0; g < 4; g++) {
            int row = w * 16 + l4 * 4 + g;
            float inv = 1.f / red_lds[row];
            int trow = t0 + row;
#pragma unroll
            for (int n = 0; n < 4; n++) {
                int col = h * 64 + n * 16 + l15;
                xatt[((size_t)(b * T_ + trow)) * C_ + col] = acc[n][g] * inv;
            }
        }
    } else {
        int sbase = (tb < 16) ? 8 + ((tb - 8) << 1)
                  : (tb < 24) ? 24 + (tb - 16) * 3
                              : 48 + ((tb - 24) << 2);
        int slot = bh * 80 + sbase + ck;
        if (l4 == 0) lpart[(size_t)slot * 64 + rloc] = lrun;
        float* pp = part + (size_t)slot * 4096;
#pragma unroll
        for (int g = 0; g < 4; g++) {
            int row = w * 16 + l4 * 4 + g;
#pragma unroll
            for (int n = 0; n < 4; n++)
                pp[row * 64 + n * 16 + l15] = acc[n][g];
        }
    }
}

// ---------------------------------------------------------------- combine partials (tb >= 8)
__global__ __launch_bounds__(256) void attn_combine_kernel(
        const float* __restrict__ part, const float* __restrict__ lpart,
        float* __restrict__ xatt) {
    int bh = blockIdx.y;
    int b = bh >> 4, h = bh & 15;
    int tb = 8 + blockIdx.x;
    int nch = (tb < 16) ? 2 : (tb < 24) ? 3 : 4;
    int sbase = (tb < 16) ? 8 + ((tb - 8) << 1)
              : (tb < 24) ? 24 + (tb - 16) * 3
                          : 48 + ((tb - 24) << 2);
    int slot0 = bh * 80 + sbase;
    int tid = threadIdx.x;
    int row = tid >> 2;
    int c0 = (tid & 3) * 16;
    float lt = 0.f;
    float4 s[4] = {{0,0,0,0},{0,0,0,0},{0,0,0,0},{0,0,0,0}};
    for (int j = 0; j < nch; j++) {
        int slot = slot0 + j;
        lt += lpart[(size_t)slot * 64 + row];
        const float* pp = part + (size_t)slot * 4096 + row * 64 + c0;
#pragma unroll
        for (int q = 0; q < 4; q++) {
            float4 v = *(const float4*)(pp + q * 4);
            s[q].x += v.x; s[q].y += v.y; s[q].z += v.z; s[q].w += v.w;
        }
    }
    float inv = 1.f / lt;
    float* op = xatt + ((size_t)(b * T_ + tb * 64 + row)) * C_ + h * 64 + c0;
#pragma unroll
    for (int q = 0; q < 4; q++) {
        float4 v = make_float4(s[q].x * inv, s[q].y * inv, s[q].z * inv, s[q].w * inv);
        *(float4*)(op + q * 4) = v;
    }
}

// ---------------------------------------------------------------- bf16 MFMA GEMM  out = A(M,K)*W(N,K)^T
// tile 128(M)x64(N), BK=32, 4 waves (round-4 proven config)
template <int MODE>
__global__ __launch_bounds__(256) void mgemm_kernel(
        const short* __restrict__ A, const short* __restrict__ W,
        const float* __restrict__ bias, short* __restrict__ outb,
        float* __restrict__ out32,
        const float* __restrict__ e0, const float* __restrict__ e1,
        const float* __restrict__ e2, const float* __restrict__ e3) {
    __shared__ short At[128 * 32];
    __shared__ short Wt[64 * 32];
    int tid = threadIdx.x;
    int w = tid >> 6, l = tid & 63;
    int i0 = blockIdx.y * 128, j0 = blockIdx.x * 64;
    int R0 = w * 32;
    const int xorb = (((l >> 4) ^ (l & 3)) << 4);
    int srow = l >> 2, schunk = l & 3;

    f32x4 acc[2][4];
#pragma unroll
    for (int m = 0; m < 2; m++)
#pragma unroll
        for (int n = 0; n < 4; n++) acc[m][n] = (f32x4){0.f, 0.f, 0.f, 0.f};

    for (int k0 = 0; k0 < C_; k0 += 32) {
#pragma unroll
        for (int half = 0; half < 2; half++) {
            int rr = half * 64 + w * 16 + srow;
            int gch = schunk ^ (rr & 3);
            async16((const char*)(A + (size_t)(i0 + rr) * C_ + k0) + gch * 16,
                    (char*)At + half * 4096 + w * 1024);
        }
        {
            int rr = w * 16 + srow;
            int gch = schunk ^ (rr & 3);
            async16((const char*)(W + (size_t)(j0 + rr) * C_ + k0) + gch * 16,
                    (char*)Wt + w * 1024);
        }
        __syncthreads();
        bf16x8 afr[2], bfr[4];
#pragma unroll
        for (int m = 0; m < 2; m++)
            afr[m] = *(const bf16x8*)((char*)At + (R0 + m * 16 + (l & 15)) * 64 + xorb);
#pragma unroll
        for (int n = 0; n < 4; n++)
            bfr[n] = *(const bf16x8*)((char*)Wt + (n * 16 + (l & 15)) * 64 + xorb);
#pragma unroll
        for (int m = 0; m < 2; m++)
#pragma unroll
            for (int n = 0; n < 4; n++)
                acc[m][n] = __builtin_amdgcn_mfma_f32_16x16x32_bf16(afr[m], bfr[n], acc[m][n], 0, 0, 0);
        __syncthreads();
    }
#pragma unroll
    for (int n = 0; n < 4; n++) {
        int col = j0 + n * 16 + (l & 15);
        float bj = bias[col];
        float tdv = (MODE == 1) ? e3[col] : 0.f;
#pragma unroll
        for (int m = 0; m < 2; m++) {
            int rbase = i0 + R0 + m * 16 + ((l >> 4) << 2);
#pragma unroll
            for (int g = 0; g < 4; g++) {
                size_t off = (size_t)(rbase + g) * C_ + col;
                float z = acc[m][n][g] + bj;
                if (MODE == 0) {
                    z = z / (1.f + __expf(-z));
                    outb[off] = f2bf(z);
                } else if (MODE == 1) {
                    float comb = e0[off] + 0.5f * e1[off] + 0.5f * z;
                    z = comb * tdv + e2[off] * (1.f - tdv);
                    outb[off] = f2bf(z);
                } else {
                    out32[off] = z;
                }
            }
        }
    }
}

// ---------------------------------------------------------------- layernorm + residual
__global__ __launch_bounds__(256) void ln_kernel(
        const float* __restrict__ proj, const float* __restrict__ x,
        const float* __restrict__ g, const float* __restrict__ bb,
        float* __restrict__ out) {
    int row = blockIdx.x;
    int tid = threadIdx.x;
    const float* pr = proj + (size_t)row * C_;
    float4 v = *(const float4*)(pr + tid * 4);
    float s = v.x + v.y + v.z + v.w;
    float s2 = v.x * v.x + v.y * v.y + v.z * v.z + v.w * v.w;
#pragma unroll
    for (int off = 32; off > 0; off >>= 1) {
        s += __shfl_down(s, off);
        s2 += __shfl_down(s2, off);
    }
    __shared__ float ws0[4], ws1[4];
    int wid = tid >> 6;
    if ((tid & 63) == 0) { ws0[wid] = s; ws1[wid] = s2; }
    __syncthreads();
    s = ws0[0] + ws0[1] + ws0[2] + ws0[3];
    s2 = ws1[0] + ws1[1] + ws1[2] + ws1[3];
    float mu = s * (1.f / C_);
    float var = s2 * (1.f / C_) - mu * mu;
    float rs = rsqrtf(var + 1e-5f);
    int c = tid * 4;
    float4 xr = *(const float4*)(x + (size_t)row * C_ + c);
    float4 gg = *(const float4*)(g + c);
    float4 bv = *(const float4*)(bb + c);
    float4 o;
    o.x = (v.x - mu) * rs * gg.x + bv.x + xr.x;
    o.y = (v.y - mu) * rs * gg.y + bv.y + xr.y;
    o.z = (v.z - mu) * rs * gg.z + bv.z + xr.z;
    o.w = (v.w - mu) * rs * gg.w + bv.w + xr.w;
    *(float4*)(out + (size_t)row * C_ + c) = o;
}

// ---------------------------------------------------------------- launch
extern "C" void kernel_launch(void* const* d_in, const int* in_sizes, int n_in,
                              void* d_out, int out_size, void* d_ws, size_t ws_size,
                              hipStream_t stream) {
    const float* x      = (const float*)d_in[0];
    const float* conv_w = (const float*)d_in[1];
    const float* conv_b = (const float*)d_in[2];
    const float* q_w    = (const float*)d_in[3];
    const float* q_b    = (const float*)d_in[4];
    const float* kv_w   = (const float*)d_in[5];
    const float* kv_b   = (const float*)d_in[6];
    const float* mem_w1 = (const float*)d_in[7];
    const float* mem_b1 = (const float*)d_in[8];
    const float* mem_w2 = (const float*)d_in[9];
    const float* mem_b2 = (const float*)d_in[10];
    const float* out_w  = (const float*)d_in[11];
    const float* out_b  = (const float*)d_in[12];
    const float* ln_g   = (const float*)d_in[13];
    const float* ln_b   = (const float*)d_in[14];
    const float* td     = (const float*)d_in[15];
    float* out = (float*)d_out;

    const size_t NTC = (size_t)B_ * T_ * C_;      // 4M
    char* p = (char*)d_ws;
    float* xconv = (float*)p;            p += NTC * 4;
    float* xatt  = (float*)p;            p += NTC * 4;
    float* qb_   = (float*)p;            p += (size_t)B_ * T_ * 32 * 4;
    float* kbT   = (float*)p;            p += (size_t)B_ * H_ * 2 * T_ * 4;
    short* xbf   = (short*)p;            p += NTC * 2;
    short* y1bf  = (short*)p;            p += NTC * 2;
    short* combbf= (short*)p;            p += NTC * 2;
    short* xvt   = (short*)p;            p += NTC * 2;
    short* wbf1  = (short*)p;            p += (size_t)C_ * C_ * 2;
    short* wbf2  = (short*)p;            p += (size_t)C_ * C_ * 2;
    short* wbf3  = (short*)p;            p += (size_t)C_ * C_ * 2;
    short* qkw   = (short*)p;            p += (size_t)64 * C_ * 2;
    // proj (16MB) aliases the head of part (40MB): part dead before mgemm<2> writes proj
    float* proj  = (float*)p;
    float* part  = (float*)p;            p += (size_t)2560 * 4096 * 4;
    float* lpart = (float*)p;            p += (size_t)2560 * 64 * 4;

    const int WN8 = (C_ * C_) / 8 / 256;
    cvt_kernel<<<(int)(NTC / 8 / 256), 256, 0, stream>>>(x, xbf);
    cvt_kernel<<<WN8, 256, 0, stream>>>(mem_w1, wbf1);
    cvt_kernel<<<WN8, 256, 0, stream>>>(mem_w2, wbf2);
    cvt_kernel<<<WN8, 256, 0, stream>>>(out_w, wbf3);
    qkcvt_kernel<<<(64 * C_) / 8 / 256, 256, 0, stream>>>(q_w, kv_w, qkw);
    vtrans_kernel<<<dim3(T_ / 64, B_ * H_), 256, 0, stream>>>(x, xvt);
    conv_kernel<<<dim3(T_ / TCV, B_ * (C_ / 256)), 256, 0, stream>>>(x, conv_w, conv_b, xconv);
    qkproj_kernel<<<(B_ * T_) / 128, 256, 0, stream>>>(xbf, qkw, q_b, kv_b, qb_, kbT);
    attn_kernel<<<dim3(80, B_ * H_), 256, 0, stream>>>(qb_, kbT, xvt, xatt, part, lpart);
    attn_combine_kernel<<<dim3(24, B_ * H_), 256, 0, stream>>>(part, lpart, xatt);
    mgemm_kernel<0><<<dim3(C_ / 64, (B_ * T_) / 128), 256, 0, stream>>>(
        xbf, wbf1, mem_b1, y1bf, nullptr, nullptr, nullptr, nullptr, nullptr);
    mgemm_kernel<1><<<dim3(C_ / 64, (B_ * T_) / 128), 256, 0, stream>>>(
        y1bf, wbf2, mem_b2, combbf, nullptr, xconv, xatt, x, td);
    mgemm_kernel<2><<<dim3(C_ / 64, (B_ * T_) / 128), 256, 0, stream>>>(
        combbf, wbf3, out_b, nullptr, proj, nullptr, nullptr, nullptr, nullptr);
    ln_kernel<<<B_ * T_, 256, 0, stream>>>(proj, x, ln_g, ln_b, out);
}

// Round 7
// 178.871 us; speedup vs baseline: 1.1512x; 1.0185x over previous
//
#include <hip/hip_runtime.h>
#include <hip/hip_bf16.h>

#define B_ 2
#define T_ 2048
#define C_ 1024
#define H_ 16
#define DV_ 64
#define KW_ 31

typedef __attribute__((ext_vector_type(8))) short bf16x8;
typedef __attribute__((ext_vector_type(4))) float f32x4;

__device__ inline short f2bf(float f) {
    __hip_bfloat16 h = __float2bfloat16(f);
    return *reinterpret_cast<short*>(&h);
}
__device__ inline float bf2f(short s) {
    unsigned int u = ((unsigned int)(unsigned short)s) << 16;
    float f;
    __builtin_memcpy(&f, &u, 4);
    return f;
}

__device__ inline void async16(const void* g, void* l) {
    __builtin_amdgcn_global_load_lds(
        (const __attribute__((address_space(1))) unsigned int*)g,
        (__attribute__((address_space(3))) unsigned int*)l, 16, 0, 0);
}

// ---------------------------------------------------------------- conv (register sliding window) -> bf16 out
#define TCV 32
__global__ __launch_bounds__(256) void conv_kernel(
        const float* __restrict__ x, const float* __restrict__ w,
        const float* __restrict__ bias, short* __restrict__ out) {
    int b = blockIdx.y >> 2;
    int c0 = (blockIdx.y & 3) * 256;
    int t0 = blockIdx.x * TCV;
    int tid = threadIdx.x;
    __shared__ float wl[256 * KW_];
    for (int i = tid; i < 256 * KW_; i += 256) wl[i] = w[c0 * KW_ + i];
    __syncthreads();
    float wr[KW_];
#pragma unroll
    for (int k = 0; k < KW_; k++) wr[k] = wl[tid * KW_ + k];
    int c = c0 + tid;
    float bi = bias[c];
    float acc[TCV];
#pragma unroll
    for (int t = 0; t < TCV; t++) acc[t] = bi;
    const float* xp = x + (size_t)b * T_ * C_ + c;
#pragma unroll
    for (int i = 0; i < TCV + KW_ - 1; i++) {
        int tt = t0 + i - 15;
        float xv = (tt >= 0 && tt < T_) ? xp[(size_t)tt * C_] : 0.f;
        int lo = (i - (KW_ - 1) > 0) ? i - (KW_ - 1) : 0;
        int hi = (i < TCV - 1) ? i : TCV - 1;
#pragma unroll
        for (int t = lo; t <= hi; t++)
            acc[t] = fmaf(xv, wr[i - t], acc[t]);
    }
    short* op = out + ((size_t)b * T_ + t0) * C_ + c;
#pragma unroll
    for (int t = 0; t < TCV; t++) op[(size_t)t * C_] = f2bf(acc[t]);
}

// ---------------------------------------------------------------- f32 -> bf16
__global__ __launch_bounds__(256) void cvt_kernel(
        const float* __restrict__ in, short* __restrict__ out) {
    int i = blockIdx.x * 256 + threadIdx.x;
    float4 v0 = ((const float4*)in)[i * 2];
    float4 v1 = ((const float4*)in)[i * 2 + 1];
    bf16x8 o;
    o[0] = f2bf(v0.x); o[1] = f2bf(v0.y); o[2] = f2bf(v0.z); o[3] = f2bf(v0.w);
    o[4] = f2bf(v1.x); o[5] = f2bf(v1.y); o[6] = f2bf(v1.z); o[7] = f2bf(v1.w);
    ((bf16x8*)out)[i] = o;
}

// ---------------------------------------------------------------- pack q_w||kv_w -> bf16 (64,1024)
__global__ __launch_bounds__(256) void qkcvt_kernel(
        const float* __restrict__ qw, const float* __restrict__ kw,
        short* __restrict__ qkw) {
    int i = blockIdx.x * 256 + threadIdx.x;
    int n = i >> 7;
    int k8 = (i & 127) * 8;
    const float* src = (n < 32 ? qw + (size_t)n * C_ : kw + (size_t)(n - 32) * C_) + k8;
    float4 v0 = *(const float4*)src;
    float4 v1 = *(const float4*)(src + 4);
    bf16x8 o;
    o[0] = f2bf(v0.x); o[1] = f2bf(v0.y); o[2] = f2bf(v0.z); o[3] = f2bf(v0.w);
    o[4] = f2bf(v1.x); o[5] = f2bf(v1.y); o[6] = f2bf(v1.z); o[7] = f2bf(v1.w);
    ((bf16x8*)qkw)[i] = o;
}

// ---------------------------------------------------------------- q/k proj via MFMA
// q -> qo row-major (B*T,32); k -> kbT [(b*16+h)*2+d][T]
__global__ __launch_bounds__(256) void qkproj_kernel(
        const short* __restrict__ A, const short* __restrict__ Wq,
        const float* __restrict__ qbias, const float* __restrict__ kbias,
        float* __restrict__ qo, float* __restrict__ kbT) {
    __shared__ short At[128 * 32];
    __shared__ short Wt[64 * 32];
    int tid = threadIdx.x;
    int w = tid >> 6, l = tid & 63;
    int i0 = blockIdx.x * 128;
    int R0 = w * 32;
    const int xorb = (((l >> 4) ^ (l & 3)) << 4);
    int srow = l >> 2, schunk = l & 3;

    f32x4 acc[2][4];
#pragma unroll
    for (int m = 0; m < 2; m++)
#pragma unroll
        for (int n = 0; n < 4; n++) acc[m][n] = (f32x4){0.f, 0.f, 0.f, 0.f};

    for (int k0 = 0; k0 < C_; k0 += 32) {
#pragma unroll
        for (int half = 0; half < 2; half++) {
            int rr = half * 64 + w * 16 + srow;
            int gch = schunk ^ (rr & 3);
            async16((const char*)(A + (size_t)(i0 + rr) * C_ + k0) + gch * 16,
                    (char*)At + half * 4096 + w * 1024);
        }
        {
            int rr = w * 16 + srow;
            int gch = schunk ^ (rr & 3);
            async16((const char*)(Wq + (size_t)rr * C_ + k0) + gch * 16,
                    (char*)Wt + w * 1024);
        }
        __syncthreads();
        bf16x8 afr[2], bfr[4];
#pragma unroll
        for (int m = 0; m < 2; m++)
            afr[m] = *(const bf16x8*)((char*)At + (R0 + m * 16 + (l & 15)) * 64 + xorb);
#pragma unroll
        for (int n = 0; n < 4; n++)
            bfr[n] = *(const bf16x8*)((char*)Wt + (n * 16 + (l & 15)) * 64 + xorb);
#pragma unroll
        for (int m = 0; m < 2; m++)
#pragma unroll
            for (int n = 0; n < 4; n++)
                acc[m][n] = __builtin_amdgcn_mfma_f32_16x16x32_bf16(afr[m], bfr[n], acc[m][n], 0, 0, 0);
        __syncthreads();
    }
#pragma unroll
    for (int n = 0; n < 4; n++) {
        int col = n * 16 + (l & 15);
        float bj = (col < 32) ? qbias[col] : kbias[col - 32];
#pragma unroll
        for (int m = 0; m < 2; m++) {
            int rbase = i0 + R0 + m * 16 + ((l >> 4) << 2);
#pragma unroll
            for (int g = 0; g < 4; g++) {
                float z = acc[m][n][g] + bj;
                int row = rbase + g;
                if (col < 32) {
                    qo[(size_t)row * 32 + col] = z;
                } else {
                    int cc = col - 32, hh = cc >> 1, dd = cc & 1;
                    int bb_ = row >> 11, tt = row & (T_ - 1);
                    kbT[(((size_t)bb_ * 16 + hh) * 2 + dd) * T_ + tt] = z;
                }
            }
        }
    }
}

// ---------------------------------------------------------------- V transpose: x (B,T,C) -> xvt (B*H, 64, T) bf16
__global__ __launch_bounds__(256) void vtrans_kernel(
        const float* __restrict__ x, short* __restrict__ xvt) {
    int bh = blockIdx.y;
    int b = bh >> 4, h = bh & 15;
    int t0 = blockIdx.x * 64;
    __shared__ float ldsT[64][65];
    int tid = threadIdx.x;
    int tl = tid >> 2;
    int d0 = (tid & 3) * 16;
    const float* xp = x + ((size_t)(b * T_ + t0 + tl)) * C_ + h * 64 + d0;
#pragma unroll
    for (int q = 0; q < 4; q++) {
        float4 v = *(const float4*)(xp + q * 4);
        ldsT[d0 + q * 4 + 0][tl] = v.x;
        ldsT[d0 + q * 4 + 1][tl] = v.y;
        ldsT[d0 + q * 4 + 2][tl] = v.z;
        ldsT[d0 + q * 4 + 3][tl] = v.w;
    }
    __syncthreads();
    int d = tid >> 2;
    int ts = (tid & 3) * 16;
    short* op = xvt + ((size_t)bh * 64 + d) * T_ + t0 + ts;
    bf16x8 o0, o1;
#pragma unroll
    for (int q = 0; q < 8; q++) {
        o0[q] = f2bf(ldsT[d][ts + q]);
        o1[q] = f2bf(ldsT[d][ts + 8 + q]);
    }
    *(bf16x8*)op = o0;
    *(bf16x8*)(op + 8) = o1;
}

// ---------------------------------------------------------------- attention (KV-split CK=1024, no-max softmax)
// QBLK=64, 4 waves x 16 rows. P in registers (A-fragment layout).
// Row sums via extra MFMA with B = ones (lands in C-layout rows directly).
__global__ __launch_bounds__(256) void attn_kernel(
        const float* __restrict__ qbuf, const float* __restrict__ kbT,
        const short* __restrict__ xvt, short* __restrict__ xattb,
        float* __restrict__ part, float* __restrict__ lpart) {
    int bh = blockIdx.y;
    int b = bh >> 4, h = bh & 15;
    int idx = 47 - (int)blockIdx.x;
    int tb, ck;
    if (idx < 16) { tb = idx; ck = 0; }
    else          { tb = 16 + ((idx - 16) >> 1); ck = (idx - 16) & 1; }
    int t0 = tb * 64;
    int kvs = ck * 1024;
    int kve = min(kvs + 1024, t0 + 64);
    int ntiles = (kve - kvs) >> 6;
    bool dom = (kve == t0 + 64);
    bool single = (tb < 16);

    int tid = threadIdx.x;
    int w = tid >> 6, l = tid & 63;
    int l15 = l & 15, l4 = l >> 4;

    __shared__ short V_lds[2 * 64 * 64];    // [buf][dv][kv] rows 128B, slot^=(dv&7)
    char* Vb = (char*)V_lds;

    const float scale = 0.02209708691f * 1.44269504089f;  // 1/sqrt(T) * log2e
    int rloc = w * 16 + l15;
    float2 q2 = *(const float2*)(qbuf + ((size_t)(b * T_ + t0 + rloc)) * 32 + h * 2);
    float qx = q2.x * scale, qy = q2.y * scale;
    const float* k0p = kbT + ((size_t)bh * 2) * T_;
    const float* k1p = k0p + T_;

    const uint4 onesu = {0x3F803F80u, 0x3F803F80u, 0x3F803F80u, 0x3F803F80u};
    bf16x8 ones = *(const bf16x8*)&onesu;

    f32x4 acc[4];
#pragma unroll
    for (int n = 0; n < 4; n++) acc[n] = (f32x4){0.f, 0.f, 0.f, 0.f};
    f32x4 acc_l = (f32x4){0.f, 0.f, 0.f, 0.f};

    // V staging: wave w covers dv rows w*16..+15 via 2 asyncs
    const char* vs0 = (const char*)xvt
        + ((((size_t)bh * 64 + w * 16 + (l >> 3)) * T_) + (size_t)(kvs + ((l & 7) ^ (l >> 3)) * 8)) * 2;
    const char* vs1 = vs0 + (size_t)8 * T_ * 2;

    async16(vs0, Vb + w * 2048);
    async16(vs1, Vb + w * 2048 + 1024);
    __syncthreads();

    for (int t = 0; t < ntiles; t++) {
        int buf = t & 1;
        if (t + 1 < ntiles) {
            size_t go = (size_t)((t + 1) * 64) * 2;
            async16(vs0 + go, Vb + (buf ^ 1) * 8192 + w * 2048);
            async16(vs1 + go, Vb + (buf ^ 1) * 8192 + w * 2048 + 1024);
        }
        // scores -> P registers (A-fragment layout)
        float kx[2][8], ky[2][8];
#pragma unroll
        for (int ks = 0; ks < 2; ks++) {
            int base = kvs + t * 64 + ks * 32 + l4 * 8;
            *(float4*)&kx[ks][0] = *(const float4*)(k0p + base);
            *(float4*)&kx[ks][4] = *(const float4*)(k0p + base + 4);
            *(float4*)&ky[ks][0] = *(const float4*)(k1p + base);
            *(float4*)&ky[ks][4] = *(const float4*)(k1p + base + 4);
        }
        bool msk = dom && (t == ntiles - 1);
        int soff = kvs + t * 64 - t0;
        bf16x8 afr[2];
#pragma unroll
        for (int ks = 0; ks < 2; ks++) {
            int kbase = soff + ks * 32 + l4 * 8;
            float pv[8];
#pragma unroll
            for (int i = 0; i < 8; i++) {
                float sc = fmaf(qx, kx[ks][i], qy * ky[ks][i]);
                float p = __builtin_amdgcn_exp2f(sc);
                if (msk) p = (kbase + i <= rloc) ? p : 0.f;
                pv[i] = p;
            }
            uint4 au;
            asm("v_cvt_pk_bf16_f32 %0, %1, %2" : "=v"(au.x) : "v"(pv[0]), "v"(pv[1]));
            asm("v_cvt_pk_bf16_f32 %0, %1, %2" : "=v"(au.y) : "v"(pv[2]), "v"(pv[3]));
            asm("v_cvt_pk_bf16_f32 %0, %1, %2" : "=v"(au.z) : "v"(pv[4]), "v"(pv[5]));
            asm("v_cvt_pk_bf16_f32 %0, %1, %2" : "=v"(au.w) : "v"(pv[6]), "v"(pv[7]));
            afr[ks] = *(bf16x8*)&au;
        }
        // PV MFMA + row-sum MFMA (B = ones)
#pragma unroll
        for (int n = 0; n < 4; n++) {
            int dv = n * 16 + l15;
            int sl0 = (l4) ^ (dv & 7);
            int sl1 = (4 + l4) ^ (dv & 7);
            bf16x8 b0 = *(const bf16x8*)(Vb + buf * 8192 + dv * 128 + sl0 * 16);
            bf16x8 b1 = *(const bf16x8*)(Vb + buf * 8192 + dv * 128 + sl1 * 16);
            acc[n] = __builtin_amdgcn_mfma_f32_16x16x32_bf16(afr[0], b0, acc[n], 0, 0, 0);
            acc[n] = __builtin_amdgcn_mfma_f32_16x16x32_bf16(afr[1], b1, acc[n], 0, 0, 0);
        }
        acc_l = __builtin_amdgcn_mfma_f32_16x16x32_bf16(afr[0], ones, acc_l, 0, 0, 0);
        acc_l = __builtin_amdgcn_mfma_f32_16x16x32_bf16(afr[1], ones, acc_l, 0, 0, 0);
        __syncthreads();
    }

    if (single) {
#pragma unroll
        for (int g = 0; g < 4; g++) {
            int row = w * 16 + l4 * 4 + g;
            float inv = 1.f / acc_l[g];
            int trow = t0 + row;
#pragma unroll
            for (int n = 0; n < 4; n++) {
                int col = h * 64 + n * 16 + l15;
                xattb[((size_t)(b * T_ + trow)) * C_ + col] = f2bf(acc[n][g] * inv);
            }
        }
    } else {
        int slot = bh * 32 + ((tb - 16) << 1) + ck;
        if (l15 == 0) {
#pragma unroll
            for (int g = 0; g < 4; g++)
                lpart[(size_t)slot * 64 + w * 16 + l4 * 4 + g] = acc_l[g];
        }
        float* pp = part + (size_t)slot * 4096;
#pragma unroll
        for (int g = 0; g < 4; g++) {
            int row = w * 16 + l4 * 4 + g;
#pragma unroll
            for (int n = 0; n < 4; n++)
                pp[row * 64 + n * 16 + l15] = acc[n][g];
        }
    }
}

// ---------------------------------------------------------------- combine partials (tb >= 16, 2 chunks)
__global__ __launch_bounds__(256) void attn_combine_kernel(
        const float* __restrict__ part, const float* __restrict__ lpart,
        short* __restrict__ xattb) {
    int bh = blockIdx.y;
    int b = bh >> 4, h = bh & 15;
    int tbi = blockIdx.x;
    int tb = 16 + tbi;
    int slot0 = bh * 32 + tbi * 2;
    int tid = threadIdx.x;
    int row = tid >> 2;
    int c0 = (tid & 3) * 16;
    float lt = lpart[(size_t)slot0 * 64 + row] + lpart[(size_t)(slot0 + 1) * 64 + row];
    float4 s[4] = {{0,0,0,0},{0,0,0,0},{0,0,0,0},{0,0,0,0}};
#pragma unroll
    for (int j = 0; j < 2; j++) {
        const float* pp = part + (size_t)(slot0 + j) * 4096 + row * 64 + c0;
#pragma unroll
        for (int q = 0; q < 4; q++) {
            float4 v = *(const float4*)(pp + q * 4);
            s[q].x += v.x; s[q].y += v.y; s[q].z += v.z; s[q].w += v.w;
        }
    }
    float inv = 1.f / lt;
    short* op = xattb + ((size_t)(b * T_ + tb * 64 + row)) * C_ + h * 64 + c0;
    bf16x8 o0, o1;
#pragma unroll
    for (int q = 0; q < 4; q++) {
        o0[q * 2 + 0] = f2bf(((const float*)&s[q >> 1])[(q & 1) * 2 + 0] * inv);
        o0[q * 2 + 1] = f2bf(((const float*)&s[q >> 1])[(q & 1) * 2 + 1] * inv);
        o1[q * 2 + 0] = f2bf(((const float*)&s[2 + (q >> 1)])[(q & 1) * 2 + 0] * inv);
        o1[q * 2 + 1] = f2bf(((const float*)&s[2 + (q >> 1)])[(q & 1) * 2 + 1] * inv);
    }
    *(bf16x8*)op = o0;
    *(bf16x8*)(op + 8) = o1;
}

// ---------------------------------------------------------------- bf16 MFMA GEMM  out = A(M,K)*W(N,K)^T
// tile 128(M)x64(N), BK=32, 4 waves, double-buffered 2-phase (stage t+1 before compute t)
template <int MODE>
__global__ __launch_bounds__(256) void mgemm_kernel(
        const short* __restrict__ A, const short* __restrict__ W,
        const float* __restrict__ bias, short* __restrict__ outb,
        float* __restrict__ out32,
        const short* __restrict__ e0, const short* __restrict__ e1,
        const float* __restrict__ e2, const float* __restrict__ e3) {
    __shared__ short At[2 * 128 * 32];
    __shared__ short Wt[2 * 64 * 32];
    int tid = threadIdx.x;
    int w = tid >> 6, l = tid & 63;
    int i0 = blockIdx.y * 128, j0 = blockIdx.x * 64;
    int R0 = w * 32;
    const int xorb = (((l >> 4) ^ (l & 3)) << 4);
    int srow = l >> 2, schunk = l & 3;
    int rrA0 = w * 16 + srow, rrA1 = 64 + w * 16 + srow;
    const char* as0 = (const char*)(A + (size_t)(i0 + rrA0) * C_) + (schunk ^ (rrA0 & 3)) * 16;
    const char* as1 = (const char*)(A + (size_t)(i0 + rrA1) * C_) + (schunk ^ (rrA1 & 3)) * 16;
    const char* wsc = (const char*)(W + (size_t)(j0 + rrA0) * C_) + (schunk ^ (rrA0 & 3)) * 16;
    char* Ab = (char*)At;
    char* Wb = (char*)Wt;

    f32x4 acc[2][4];
#pragma unroll
    for (int m = 0; m < 2; m++)
#pragma unroll
        for (int n = 0; n < 4; n++) acc[m][n] = (f32x4){0.f, 0.f, 0.f, 0.f};

    // prologue: stage k-step 0 into buf 0
    async16(as0, Ab + w * 1024);
    async16(as1, Ab + 4096 + w * 1024);
    async16(wsc, Wb + w * 1024);

    for (int ks = 0; ks < 32; ks++) {
        int buf = ks & 1;
        __syncthreads();                       // staged buf ready; prev reads of buf^1 done
        if (ks + 1 < 32) {
            size_t go = (size_t)(ks + 1) * 64; // 32 bf16 = 64B
            async16(as0 + go, Ab + (buf ^ 1) * 8192 + w * 1024);
            async16(as1 + go, Ab + (buf ^ 1) * 8192 + 4096 + w * 1024);
            async16(wsc + go, Wb + (buf ^ 1) * 4096 + w * 1024);
        }
        bf16x8 afr[2], bfr[4];
#pragma unroll
        for (int m = 0; m < 2; m++)
            afr[m] = *(const bf16x8*)(Ab + buf * 8192 + (R0 + m * 16 + (l & 15)) * 64 + xorb);
#pragma unroll
        for (int n = 0; n < 4; n++)
            bfr[n] = *(const bf16x8*)(Wb + buf * 4096 + (n * 16 + (l & 15)) * 64 + xorb);
#pragma unroll
        for (int m = 0; m < 2; m++)
#pragma unroll
            for (int n = 0; n < 4; n++)
                acc[m][n] = __builtin_amdgcn_mfma_f32_16x16x32_bf16(afr[m], bfr[n], acc[m][n], 0, 0, 0);
    }
    // epilogue
#pragma unroll
    for (int n = 0; n < 4; n++) {
        int col = j0 + n * 16 + (l & 15);
        float bj = bias[col];
        float tdv = (MODE == 1) ? e3[col] : 0.f;
#pragma unroll
        for (int m = 0; m < 2; m++) {
            int rbase = i0 + R0 + m * 16 + ((l >> 4) << 2);
#pragma unroll
            for (int g = 0; g < 4; g++) {
                size_t off = (size_t)(rbase + g) * C_ + col;
                float z = acc[m][n][g] + bj;
                if (MODE == 0) {
                    z = z / (1.f + __expf(-z));
                    outb[off] = f2bf(z);
                } else if (MODE == 1) {
                    float comb = bf2f(e0[off]) + 0.5f * bf2f(e1[off]) + 0.5f * z;
                    z = comb * tdv + e2[off] * (1.f - tdv);
                    outb[off] = f2bf(z);
                } else {
                    out32[off] = z;
                }
            }
        }
    }
}

// ---------------------------------------------------------------- layernorm + residual
__global__ __launch_bounds__(256) void ln_kernel(
        const float* __restrict__ proj, const float* __restrict__ x,
        const float* __restrict__ g, const float* __restrict__ bb,
        float* __restrict__ out) {
    int row = blockIdx.x;
    int tid = threadIdx.x;
    const float* pr = proj + (size_t)row * C_;
    float4 v = *(const float4*)(pr + tid * 4);
    float s = v.x + v.y + v.z + v.w;
    float s2 = v.x * v.x + v.y * v.y + v.z * v.z + v.w * v.w;
#pragma unroll
    for (int off = 32; off > 0; off >>= 1) {
        s += __shfl_down(s, off);
        s2 += __shfl_down(s2, off);
    }
    __shared__ float ws0[4], ws1[4];
    int wid = tid >> 6;
    if ((tid & 63) == 0) { ws0[wid] = s; ws1[wid] = s2; }
    __syncthreads();
    s = ws0[0] + ws0[1] + ws0[2] + ws0[3];
    s2 = ws1[0] + ws1[1] + ws1[2] + ws1[3];
    float mu = s * (1.f / C_);
    float var = s2 * (1.f / C_) - mu * mu;
    float rs = rsqrtf(var + 1e-5f);
    int c = tid * 4;
    float4 xr = *(const float4*)(x + (size_t)row * C_ + c);
    float4 gg = *(const float4*)(g + c);
    float4 bv = *(const float4*)(bb + c);
    float4 o;
    o.x = (v.x - mu) * rs * gg.x + bv.x + xr.x;
    o.y = (v.y - mu) * rs * gg.y + bv.y + xr.y;
    o.z = (v.z - mu) * rs * gg.z + bv.z + xr.z;
    o.w = (v.w - mu) * rs * gg.w + bv.w + xr.w;
    *(float4*)(out + (size_t)row * C_ + c) = o;
}

// ---------------------------------------------------------------- launch
extern "C" void kernel_launch(void* const* d_in, const int* in_sizes, int n_in,
                              void* d_out, int out_size, void* d_ws, size_t ws_size,
                              hipStream_t stream) {
    const float* x      = (const float*)d_in[0];
    const float* conv_w = (const float*)d_in[1];
    const float* conv_b = (const float*)d_in[2];
    const float* q_w    = (const float*)d_in[3];
    const float* q_b    = (const float*)d_in[4];
    const float* kv_w   = (const float*)d_in[5];
    const float* kv_b   = (const float*)d_in[6];
    const float* mem_w1 = (const float*)d_in[7];
    const float* mem_b1 = (const float*)d_in[8];
    const float* mem_w2 = (const float*)d_in[9];
    const float* mem_b2 = (const float*)d_in[10];
    const float* out_w  = (const float*)d_in[11];
    const float* out_b  = (const float*)d_in[12];
    const float* ln_g   = (const float*)d_in[13];
    const float* ln_b   = (const float*)d_in[14];
    const float* td     = (const float*)d_in[15];
    float* out = (float*)d_out;

    const size_t NTC = (size_t)B_ * T_ * C_;      // 4M
    char* p = (char*)d_ws;
    short* xconvb = (short*)p;           p += NTC * 2;
    short* xattb  = (short*)p;           p += NTC * 2;
    float* qb_   = (float*)p;            p += (size_t)B_ * T_ * 32 * 4;
    float* kbT   = (float*)p;            p += (size_t)B_ * H_ * 2 * T_ * 4;
    short* xbf   = (short*)p;            p += NTC * 2;
    short* y1bf  = (short*)p;            p += NTC * 2;
    short* combbf= (short*)p;            p += NTC * 2;
    short* xvt   = (short*)p;            p += NTC * 2;
    short* wbf1  = (short*)p;            p += (size_t)C_ * C_ * 2;
    short* wbf2  = (short*)p;            p += (size_t)C_ * C_ * 2;
    short* wbf3  = (short*)p;            p += (size_t)C_ * C_ * 2;
    short* qkw   = (short*)p;            p += (size_t)64 * C_ * 2;
    // proj (16MB) aliases part (16MB): part dead after combine, proj written later
    float* proj  = (float*)p;
    float* part  = (float*)p;            p += (size_t)1024 * 4096 * 4;
    float* lpart = (float*)p;            p += (size_t)1024 * 64 * 4;

    const int WN8 = (C_ * C_) / 8 / 256;
    cvt_kernel<<<(int)(NTC / 8 / 256), 256, 0, stream>>>(x, xbf);
    cvt_kernel<<<WN8, 256, 0, stream>>>(mem_w1, wbf1);
    cvt_kernel<<<WN8, 256, 0, stream>>>(mem_w2, wbf2);
    cvt_kernel<<<WN8, 256, 0, stream>>>(out_w, wbf3);
    qkcvt_kernel<<<(64 * C_) / 8 / 256, 256, 0, stream>>>(q_w, kv_w, qkw);
    vtrans_kernel<<<dim3(T_ / 64, B_ * H_), 256, 0, stream>>>(x, xvt);
    conv_kernel<<<dim3(T_ / TCV, B_ * (C_ / 256)), 256, 0, stream>>>(x, conv_w, conv_b, xconvb);
    qkproj_kernel<<<(B_ * T_) / 128, 256, 0, stream>>>(xbf, qkw, q_b, kv_b, qb_, kbT);
    attn_kernel<<<dim3(48, B_ * H_), 256, 0, stream>>>(qb_, kbT, xvt, xattb, part, lpart);
    attn_combine_kernel<<<dim3(16, B_ * H_), 256, 0, stream>>>(part, lpart, xattb);
    mgemm_kernel<0><<<dim3(C_ / 64, (B_ * T_) / 128), 256, 0, stream>>>(
        xbf, wbf1, mem_b1, y1bf, nullptr, nullptr, nullptr, nullptr, nullptr);
    mgemm_kernel<1><<<dim3(C_ / 64, (B_ * T_) / 128), 256, 0, stream>>>(
        y1bf, wbf2, mem_b2, combbf, nullptr, xconvb, xattb, x, td);
    mgemm_kernel<2><<<dim3(C_ / 64, (B_ * T_) / 128), 256, 0, stream>>>(
        combbf, wbf3, out_b, nullptr, proj, nullptr, nullptr, nullptr, nullptr);
    ln_kernel<<<B_ * T_, 256, 0, stream>>>(proj, x, ln_g, ln_b, out);
}